// Round 14
// baseline (381.748 us; speedup 1.0000x reference)
//
#include <hip/hip_runtime.h>

#define NKER 84
#define NCH 9
#define SEQ 2048
#define NBATCH 64
#define NDIL 26
#define NFTOT 9996
#define MAXNF 15
#define NSLOT 14
#define NXCD 8
#define WPB 2                    // waves per block (R9 optimum)
#define NPAIR 3                  // k-pairs per block: 84 / (2*14)

// Static MiniRocket config for SEQ_LEN=2048, NUM_FEATURES=10000 (replicates numpy float64 logspace)
static constexpr int DILS[NDIL]   = {1,2,3,4,5,7,8,10,12,14,17,20,25,29,35,42,51,61,73,87,104,125,149,178,213,255};
static constexpr int NFDS[NDIL]   = {15,12,4,4,8,4,4,4,4,4,4,4,4,4,4,4,4,4,3,3,3,3,3,3,3,3};
static constexpr int CBASES[NDIL] = {0,1260,2268,2604,2940,3612,3948,4284,4620,4956,5292,5628,5964,6300,6636,6972,7308,7644,7980,8232,8484,8736,8988,9240,9492,9744};

// 2-float vector with 4-byte alignment: legal at odd dword offsets; compiler
// emits ds_read_b64 (aligned) or ds_read2_b32 (unaligned) — one DS instruction
// for two consecutive taps' elements either way.
typedef float f32x2u __attribute__((ext_vector_type(2), aligned(4)));

// Force a (known-uniform) float into an SGPR. Scalar v_fma/v_cmp accept one
// SGPR operand at full rate, so wave-uniform constants (w, bias) cost 0 VGPRs.
// R7+R12: packed VOP3P f32 is a dead end (VGPR-only sources AND half-rate).
__device__ __forceinline__ float uniform_f(float v) {
    return __builtin_bit_cast(float, __builtin_amdgcn_readfirstlane(__builtin_bit_cast(int, v)));
}

// Packed f32 add, all-VGPR operands (build-phase accumulate only).
__device__ __forceinline__ f32x2u pk_add(f32x2u a, f32x2u b) {
    f32x2u d;
    asm("v_pk_add_f32 %0, %1, %2" : "=v"(d) : "v"(a), "v"(b));
    return d;
}

template <int I>
__device__ __forceinline__ void body(const float* __restrict__ kw,
                                     const float* __restrict__ cc,
                                     const float* __restrict__ bias,
                                     float* __restrict__ out,
                                     const float* __restrict__ xb,    // x + b*NCH*SEQ
                                     float (* __restrict__ ybuf)[SEQ],       // [2][SEQ]: k-pair buffers
                                     int (* __restrict__ cbuf)[WPB][MAXNF],  // [2][WPB][MAXNF]
                                     int b, int slot, int lane, int wv) {
    constexpr int D = DILS[I];
    constexpr int NF = NFDS[I];
    constexpr int P = 4 * D;
    constexpr int PAD1 = I & 1;
    constexpr int CBASE = CBASES[I];
    constexpr int RANGE = SEQ - 2 * P;          // valid-region length (>0 for all D)
    // full-range loop split (compile-time): interior j has all taps in [0, SEQ) for every lane
    constexpr int JLO = (P + 63) / 64;                      // first fully-interior 64-iter
    constexpr int JHI = (SEQ - P - 64) / 64;                // last fully-interior 64-iter (incl)
    constexpr int NI  = (JHI + 1 > JLO) ? (JHI + 1 - JLO) : 0;   // # interior 64-iters
    constexpr int NI2 = NI / 2;                             // 128-el pair-iters
    constexpr bool IBR = (NI & 1) != 0;                     // one bridge 64-iter
    constexpr int JT0 = (JHI + 1 > JLO) ? (JHI + 1) : JLO;  // start of trailing boundary
    // valid-region decomposition: pairs + optional 64-bridge + clamped partial
    constexpr int MV2 = RANGE / 128;
    constexpr int TV1 = (RANGE - MV2 * 128) / 64;           // 0 or 1
    constexpr int REM = RANGE - MV2 * 128 - TV1 * 64;       // 0..63

    const float4* __restrict__ xb4 = (const float4*)xb;     // [NCH][SEQ/4]

#define MRF_MB(K, DST) { \
        int mb_ = 0; \
        for (int c = 0; c < NCH; ++c) \
            if (cc[(I * NCH + c) * NKER + (K)] != 0.0f) mb_ |= (1 << c); \
        DST = __builtin_amdgcn_readfirstlane(mb_); }

    for (int g = 0; g < NPAIR; ++g) {
        const int k0 = slot + g * (2 * NSLOT);              // pair: k0, k0+NSLOT (same parity)

        // barrier A: previous group's conv reads + cbuf merge-reads done before
        // this group's build overwrites ybuf / publishes overwrite cbuf.
        __syncthreads();

        int mb0, mb1;
        MRF_MB(k0, mb0)
        MRF_MB(k0 + NSLOT, mb1)

        // ---- build BOTH y buffers from ONE x pass (wave wv builds half wv).
        //      it-outer / c-inner: acc live set = 2 float4 (8 VGPR) < R9's 16,
        //      protecting the 64-VGPR granule. x loads serve both kernels:
        //      18 float4 loads per k vs R9's 36 -> L2 build traffic halved. ----
#pragma unroll
        for (int it = 0; it < SEQ / 512; ++it) {
            f32x2u a0l = {0.f, 0.f}, a0h = {0.f, 0.f};
            f32x2u a1l = {0.f, 0.f}, a1h = {0.f, 0.f};
#pragma unroll
            for (int c = 0; c < NCH; ++c) {
                if ((mb0 | mb1) & (1 << c)) {
                    float4 v = xb4[c * (SEQ / 4) + wv * (SEQ / 8) + it * 64 + lane];
                    if (mb0 & (1 << c)) {
                        a0l = pk_add(a0l, (f32x2u){v.x, v.y});
                        a0h = pk_add(a0h, (f32x2u){v.z, v.w});
                    }
                    if (mb1 & (1 << c)) {
                        a1l = pk_add(a1l, (f32x2u){v.x, v.y});
                        a1h = pk_add(a1h, (f32x2u){v.z, v.w});
                    }
                }
            }
            ((float4*)ybuf[0])[wv * (SEQ / 8) + it * 64 + lane] =
                make_float4(a0l.x, a0l.y, a0h.x, a0h.y);
            ((float4*)ybuf[1])[wv * (SEQ / 8) + it * 64 + lane] =
                make_float4(a1l.x, a1l.y, a1h.x, a1h.y);
        }
        // barrier B: both buffers complete before conv reads cross-half taps
        __syncthreads();

        // ---- conv k0 then k0+NSLOT sequentially (register pressure == R9:
        //      config/w/bs/cnt reused across the kk loop) ----
        for (int kk = 0; kk < 2; ++kk) {
            const int k = k0 + kk * NSLOT;
            const float* __restrict__ y = ybuf[kk];

            int j0 = -1, j1 = -1, j2 = -1, no = 0;
            for (int j = 0; j < 9; ++j) {
                if (kw[k * 9 + j] > 0.0f) {
                    if (no == 0) j0 = j; else if (no == 1) j1 = j; else j2 = j;
                    ++no;
                }
            }
            j0 = __builtin_amdgcn_readfirstlane(j0);
            j1 = __builtin_amdgcn_readfirstlane(j1);
            j2 = __builtin_amdgcn_readfirstlane(j2);

            float w[9];
#pragma unroll
            for (int jj = 0; jj < 9; ++jj)
                w[jj] = uniform_f((jj == j0 || jj == j1 || jj == j2) ? 2.0f : -1.0f);

            float bs[NF];
#pragma unroll
            for (int f = 0; f < NF; ++f)
                bs[f] = uniform_f(bias[(I * NKER + k) * MAXNF + f]);

            int cnt[NF];
#pragma unroll
            for (int f = 0; f < NF; ++f) cnt[f] = 0;

#define MRF_ITER2(TB) { \
                const int e0_ = (TB) + 2 * lane - 4 * D; \
                float CvA = 0.0f, CvB = 0.0f; \
                _Pragma("unroll") \
                for (int jj = 0; jj < 9; ++jj) { \
                    f32x2u p_ = *(const f32x2u*)(y + e0_ + jj * D); \
                    CvA = __builtin_fmaf(w[jj], p_.x, CvA); \
                    CvB = __builtin_fmaf(w[jj], p_.y, CvB); \
                } \
                _Pragma("unroll") \
                for (int f = 0; f < NF; ++f) \
                    cnt[f] += __popcll(__ballot(CvA > bs[f])) + __popcll(__ballot(CvB > bs[f])); }

#define MRF_ITER(TB) { \
                const int t_ = (TB) + lane; \
                float Cv = 0.0f; \
                _Pragma("unroll") \
                for (int jj = 0; jj < 9; ++jj) \
                    Cv = __builtin_fmaf(w[jj], y[t_ + (jj - 4) * D], Cv); \
                _Pragma("unroll") \
                for (int f = 0; f < NF; ++f) \
                    cnt[f] += __popcll(__ballot(Cv > bs[f])); }

            // boundary iter: callers fully unroll -> per-tap window tests fold
#define MRF_MASKED(TB) { \
                const int t_ = (TB) + lane; \
                float Cv = 0.0f; \
                _Pragma("unroll") \
                for (int jj = 0; jj < 9; ++jj) { \
                    const int lo_ = (TB) + (jj - 4) * D; \
                    if (lo_ >= 0 && lo_ + 63 < SEQ) { \
                        Cv = __builtin_fmaf(w[jj], y[t_ + (jj - 4) * D], Cv); \
                    } else if (lo_ + 63 >= 0 && lo_ < SEQ) { \
                        const int u_ = t_ + (jj - 4) * D; \
                        float v_ = y[u_ & (SEQ - 1)]; \
                        v_ = ((unsigned)u_ < (unsigned)SEQ) ? v_ : 0.0f; \
                        Cv = __builtin_fmaf(w[jj], v_, Cv); \
                    } \
                } \
                _Pragma("unroll") \
                for (int f = 0; f < NF; ++f) \
                    cnt[f] += __popcll(__ballot(Cv > bs[f])); }

            // conv: waves split the t-range into disjoint alternating chunks
            if ((k & 1) == PAD1) {
                // full padded range [0, SEQ): masked lead + paired interior + masked trail
#pragma unroll
                for (int j = 0; j < JLO; ++j)
                    if (((j >> 1) & 1) == wv) MRF_MASKED(j * 64)
#pragma unroll 2
                for (int a = wv; a < NI2; a += 2) MRF_ITER2(JLO * 64 + a * 128)
                if constexpr (IBR)
                    if ((NI2 & 1) == wv) MRF_ITER(JLO * 64 + NI2 * 128)
#pragma unroll
                for (int j = JT0; j < SEQ / 64; ++j)
                    if (((j >> 1) & 1) == wv) MRF_MASKED(j * 64)
            } else {
                // valid region [P, SEQ-P): paired main + bridge + clamped partial
#pragma unroll 2
                for (int a = wv; a < MV2; a += 2) MRF_ITER2(P + a * 128)
                if constexpr (TV1)
                    if ((MV2 & 1) == wv) MRF_ITER(P + MV2 * 128)
                if constexpr (REM != 0) {
                    if (((MV2 + TV1) & 1) == wv) {
                        const int t = P + MV2 * 128 + TV1 * 64 + lane;
                        const int tr = (t < SEQ - P) ? t : (SEQ - P - 1);
                        const float* __restrict__ pb = y + tr - 4 * D;
                        float Cv = 0.0f;
#pragma unroll
                        for (int jj = 0; jj < 9; ++jj)
                            Cv = __builtin_fmaf(w[jj], pb[jj * D], Cv);
                        Cv = (t < SEQ - P) ? Cv : -3.402823466e38f;  // poison -> never > bias
#pragma unroll
                        for (int f = 0; f < NF; ++f)
                            cnt[f] += __popcll(__ballot(Cv > bs[f]));
                    }
                }
            }

#undef MRF_ITER2
#undef MRF_ITER
#undef MRF_MASKED

            // publish this wave's counts (cnt dies here -> no extra liveness)
            if (lane == 0) {
#pragma unroll
                for (int f = 0; f < NF; ++f) cbuf[kk][wv][f] = cnt[f];
            }
        }

        // barrier C: both k's counts visible
        __syncthreads();

        // ---- merge + write: wave wv's lane0 handles k = k0 + wv*NSLOT ----
        if (lane == 0) {
            const int k = k0 + wv * NSLOT;
            const bool full = ((k & 1) == PAD1);
            const float invT = full ? (1.0f / (float)SEQ) : (1.0f / (float)RANGE);
            const int pos = full ? ((k - PAD1) >> 1) : (42 + ((k - (1 - PAD1)) >> 1));
            const int colb = CBASE + pos * NF;
#pragma unroll
            for (int f = 0; f < NF; ++f)
                out[(size_t)b * NFTOT + colb + f] =
                    (float)(cbuf[wv][0][f] + cbuf[wv][1][f]) * invT;
        }
    }

#undef MRF_MB
}

// Ledger (rounds 0-14):
//  - Residency: tracks the VGPR ceiling ONLY (R13: 2x LDS -> occ unchanged
//    44%; R12: VGPR 64->80 bucket -> occ -24%, dur +32%). VGPR granule = 16,
//    waves/SIMD = floor(512/rounded). KEEP VGPR AT 64 EXACTLY.
//  - WPB=2 optimum (R10/R11: WPB=4 = +54% VALU). Packed f32 FMA dead (R7/R12).
//    Caps: generous (128) only (R1 spill / R10 remat). Barriers were never
//    the bottleneck (R13: 9->4 barriers, no gain).
//  - R14: paired-k build — one x pass fills ybuf[0] (k) and ybuf[1] (k+14):
//    x L2 traffic halved (~5.2 -> 2.6 GB/dispatch), barriers/k halved,
//    grid halved. Conv + VGPR structure byte-identical to R9.
extern "C" __global__ void __launch_bounds__(WPB * 64)
__attribute__((amdgpu_num_vgpr(128)))
mrf_kernel(const float* __restrict__ x, const float* __restrict__ kw,
           const float* __restrict__ cc, const float* __restrict__ bias,
           float* __restrict__ out) {
    __shared__ __align__(16) float ybuf[2][SEQ];     // 16KB: one buffer per k of the pair
    __shared__ int cbuf[2][WPB][MAXNF];              // per-k count publish (240B)

    // XCD-chunked bijective swizzle (proven round 0): XCD x owns a contiguous
    // chunk of (b,i,s) with b slowest -> concurrent blocks on an XCD share ~1-2
    // b values -> x slices stay L2-resident. (R1 measured the alternative:
    // i slowest -> 1.75 GB of L2 misses, 1.7x slower.)
    constexpr int NGRID = NDIL * NBATCH * NSLOT;       // 23296
    constexpr int CHUNK = NGRID / NXCD;                // 2912
    const int blk = (blockIdx.x % NXCD) * CHUNK + blockIdx.x / NXCD;

    const int s = blk % NSLOT;
    const int rest = blk / NSLOT;
    const int i = rest % NDIL;              // dilation index
    const int b = rest / NDIL;              // batch index (slowest)
    const int lane = threadIdx.x & 63;
    // wave id, forced to SGPR so work-split guards are scalar branches
    const int wv = __builtin_amdgcn_readfirstlane((int)(threadIdx.x >> 6));

    const float* xb = x + (size_t)b * (NCH * SEQ);

    switch (i) {
#define MRF_CASE(I) case I: body<I>(kw, cc, bias, out, xb, ybuf, cbuf, b, s, lane, wv); break;
        MRF_CASE(0)  MRF_CASE(1)  MRF_CASE(2)  MRF_CASE(3)  MRF_CASE(4)
        MRF_CASE(5)  MRF_CASE(6)  MRF_CASE(7)  MRF_CASE(8)  MRF_CASE(9)
        MRF_CASE(10) MRF_CASE(11) MRF_CASE(12) MRF_CASE(13) MRF_CASE(14)
        MRF_CASE(15) MRF_CASE(16) MRF_CASE(17) MRF_CASE(18) MRF_CASE(19)
        MRF_CASE(20) MRF_CASE(21) MRF_CASE(22) MRF_CASE(23) MRF_CASE(24)
        MRF_CASE(25)
#undef MRF_CASE
    }
}

extern "C" void kernel_launch(void* const* d_in, const int* in_sizes, int n_in,
                              void* d_out, int out_size, void* d_ws, size_t ws_size,
                              hipStream_t stream) {
    (void)in_sizes; (void)n_in; (void)d_ws; (void)ws_size; (void)out_size;
    const float* x    = (const float*)d_in[0];
    const float* kw   = (const float*)d_in[1];
    const float* cc   = (const float*)d_in[2];
    const float* bias = (const float*)d_in[3];
    float* out = (float*)d_out;

    mrf_kernel<<<dim3(NDIL * NBATCH * NSLOT), dim3(WPB * 64), 0, stream>>>(x, kw, cc, bias, out);
}

// Round 15
// 330.011 us; speedup vs baseline: 1.1568x; 1.1568x over previous
//
#include <hip/hip_runtime.h>

#define NKER 84
#define NCH 9
#define SEQ 2048
#define NBATCH 64
#define NDIL 26
#define NFTOT 9996
#define MAXNF 15
#define NSLOT 28
#define NXCD 8
#define NUNIT 2                  // independent 2-wave R9-units per block
#define NSPAIR (NSLOT / NUNIT)   // 14 slot-pairs in the grid

// Static MiniRocket config for SEQ_LEN=2048, NUM_FEATURES=10000 (replicates numpy float64 logspace)
static constexpr int DILS[NDIL]   = {1,2,3,4,5,7,8,10,12,14,17,20,25,29,35,42,51,61,73,87,104,125,149,178,213,255};
static constexpr int NFDS[NDIL]   = {15,12,4,4,8,4,4,4,4,4,4,4,4,4,4,4,4,4,3,3,3,3,3,3,3,3};
static constexpr int CBASES[NDIL] = {0,1260,2268,2604,2940,3612,3948,4284,4620,4956,5292,5628,5964,6300,6636,6972,7308,7644,7980,8232,8484,8736,8988,9240,9492,9744};

// 2-float vector with 4-byte alignment: legal at odd dword offsets; compiler
// emits ds_read_b64 (aligned) or ds_read2_b32 (unaligned) — one DS instruction
// for two consecutive taps' elements either way.
typedef float f32x2u __attribute__((ext_vector_type(2), aligned(4)));

// Force a (known-uniform) float into an SGPR. Scalar v_fma/v_cmp accept one
// SGPR operand at full rate, so wave-uniform constants (w, bias) cost 0 VGPRs.
// R7+R12: packed VOP3P f32 is a dead end (VGPR-only sources AND half-rate).
__device__ __forceinline__ float uniform_f(float v) {
    return __builtin_bit_cast(float, __builtin_amdgcn_readfirstlane(__builtin_bit_cast(int, v)));
}

// Packed f32 add, all-VGPR operands (build-phase accumulate only).
__device__ __forceinline__ f32x2u pk_add(f32x2u a, f32x2u b) {
    f32x2u d;
    asm("v_pk_add_f32 %0, %1, %2" : "=v"(d) : "v"(a), "v"(b));
    return d;
}

// ===== R9 body, verbatim (317us best): 2 waves share one ybuf; wave wv
// builds half wv, conv split in alternating chunks, ballot+popcount counts,
// wave1 publishes via cbuf, wave0 merges+writes. =====
template <int I>
__device__ __forceinline__ void body(const float* __restrict__ kw,
                                     const float* __restrict__ cc,
                                     const float* __restrict__ bias,
                                     float* __restrict__ out,
                                     const float* __restrict__ xb,   // x + b*NCH*SEQ
                                     float* __restrict__ y,          // this unit's 8KB ybuf
                                     int* __restrict__ cbuf,         // this unit's NF-int merge buffer
                                     int b, int slot, int lane, int wv) {
    constexpr int D = DILS[I];
    constexpr int NF = NFDS[I];
    constexpr int P = 4 * D;
    constexpr int PAD1 = I & 1;
    constexpr int CBASE = CBASES[I];
    constexpr int RANGE = SEQ - 2 * P;          // valid-region length (>0 for all D)
    // full-range loop split (compile-time): interior j has all taps in [0, SEQ) for every lane
    constexpr int JLO = (P + 63) / 64;                      // first fully-interior 64-iter
    constexpr int JHI = (SEQ - P - 64) / 64;                // last fully-interior 64-iter (incl)
    constexpr int NI  = (JHI + 1 > JLO) ? (JHI + 1 - JLO) : 0;   // # interior 64-iters
    constexpr int NI2 = NI / 2;                             // 128-el pair-iters
    constexpr bool IBR = (NI & 1) != 0;                     // one bridge 64-iter
    constexpr int JT0 = (JHI + 1 > JLO) ? (JHI + 1) : JLO;  // start of trailing boundary
    // valid-region decomposition: pairs + optional 64-bridge + clamped partial
    constexpr int MV2 = RANGE / 128;
    constexpr int TV1 = (RANGE - MV2 * 128) / 64;           // 0 or 1
    constexpr int REM = RANGE - MV2 * 128 - TV1 * 64;       // 0..63

    const float4* __restrict__ xb4 = (const float4*)xb;     // [NCH][SEQ/4]

    for (int k = slot; k < NKER; k += NSLOT) {
        // barrier A: previous k's conv reads + merge reads done before this
        // k's build overwrites ybuf. (Shared by both units; slot pairing
        // s/s+14 has equal parity -> phases are length-identical -> aligned.)
        __syncthreads();

        // ---- per-kernel config (wave-uniform scalars) ----
        int mb = 0;
        for (int c = 0; c < NCH; ++c)
            if (cc[(I * NCH + c) * NKER + k] != 0.0f) mb |= (1 << c);
        mb = __builtin_amdgcn_readfirstlane(mb);

        int j0 = -1, j1 = -1, j2 = -1, no = 0;
        for (int j = 0; j < 9; ++j) {
            if (kw[k * 9 + j] > 0.0f) {
                if (no == 0) j0 = j; else if (no == 1) j1 = j; else j2 = j;
                ++no;
            }
        }
        j0 = __builtin_amdgcn_readfirstlane(j0);
        j1 = __builtin_amdgcn_readfirstlane(j1);
        j2 = __builtin_amdgcn_readfirstlane(j2);

        // tap weights and bias thresholds: wave-uniform -> SGPRs
        float w[9];
#pragma unroll
        for (int jj = 0; jj < 9; ++jj)
            w[jj] = uniform_f((jj == j0 || jj == j1 || jj == j2) ? 2.0f : -1.0f);

        float bs[NF];
#pragma unroll
        for (int f = 0; f < NF; ++f)
            bs[f] = uniform_f(bias[(I * NKER + k) * MAXNF + f]);

        // ---- build y[t]: wave wv builds half h=wv ----
        {
            const int h = wv;
            f32x2u acc2[2 * (SEQ / 512)];
#pragma unroll
            for (int it = 0; it < 2 * (SEQ / 512); ++it)
                acc2[it] = (f32x2u){0.f, 0.f};
#pragma unroll
            for (int c = 0; c < NCH; ++c) {
                if (mb & (1 << c)) {
#pragma unroll
                    for (int it = 0; it < SEQ / 512; ++it) {
                        float4 v = xb4[c * (SEQ / 4) + h * (SEQ / 8) + it * 64 + lane];
                        acc2[2 * it]     = pk_add(acc2[2 * it],     (f32x2u){v.x, v.y});
                        acc2[2 * it + 1] = pk_add(acc2[2 * it + 1], (f32x2u){v.z, v.w});
                    }
                }
            }
#pragma unroll
            for (int it = 0; it < SEQ / 512; ++it)
                ((float4*)y)[h * (SEQ / 8) + it * 64 + lane] =
                    make_float4(acc2[2 * it].x, acc2[2 * it].y,
                                acc2[2 * it + 1].x, acc2[2 * it + 1].y);
        }
        // barrier B: both halves of y visible before conv reads cross-half taps
        __syncthreads();

        // wave-total counters via ballot+popcount (scalar-pipe accumulate)
        int cnt[NF];
#pragma unroll
        for (int f = 0; f < NF; ++f) cnt[f] = 0;

#define MRF_ITER2(TB) { \
            const int e0_ = (TB) + 2 * lane - 4 * D; \
            float CvA = 0.0f, CvB = 0.0f; \
            _Pragma("unroll") \
            for (int jj = 0; jj < 9; ++jj) { \
                f32x2u p_ = *(const f32x2u*)(y + e0_ + jj * D); \
                CvA = __builtin_fmaf(w[jj], p_.x, CvA); \
                CvB = __builtin_fmaf(w[jj], p_.y, CvB); \
            } \
            _Pragma("unroll") \
            for (int f = 0; f < NF; ++f) \
                cnt[f] += __popcll(__ballot(CvA > bs[f])) + __popcll(__ballot(CvB > bs[f])); }

#define MRF_ITER(TB) { \
            const int t_ = (TB) + lane; \
            float Cv = 0.0f; \
            _Pragma("unroll") \
            for (int jj = 0; jj < 9; ++jj) \
                Cv = __builtin_fmaf(w[jj], y[t_ + (jj - 4) * D], Cv); \
            _Pragma("unroll") \
            for (int f = 0; f < NF; ++f) \
                cnt[f] += __popcll(__ballot(Cv > bs[f])); }

        // boundary iter: callers fully unroll -> per-tap window tests fold
#define MRF_MASKED(TB) { \
            const int t_ = (TB) + lane; \
            float Cv = 0.0f; \
            _Pragma("unroll") \
            for (int jj = 0; jj < 9; ++jj) { \
                const int lo_ = (TB) + (jj - 4) * D; \
                if (lo_ >= 0 && lo_ + 63 < SEQ) { \
                    Cv = __builtin_fmaf(w[jj], y[t_ + (jj - 4) * D], Cv); \
                } else if (lo_ + 63 >= 0 && lo_ < SEQ) { \
                    const int u_ = t_ + (jj - 4) * D; \
                    float v_ = y[u_ & (SEQ - 1)]; \
                    v_ = ((unsigned)u_ < (unsigned)SEQ) ? v_ : 0.0f; \
                    Cv = __builtin_fmaf(w[jj], v_, Cv); \
                } \
            } \
            _Pragma("unroll") \
            for (int f = 0; f < NF; ++f) \
                cnt[f] += __popcll(__ballot(Cv > bs[f])); }

        // ---- conv: the unit's 2 waves split the t-range into disjoint chunks ----
        if ((k & 1) == PAD1) {
            // full padded range [0, SEQ): masked lead + paired interior + masked trail
#pragma unroll
            for (int j = 0; j < JLO; ++j)
                if (((j >> 1) & 1) == wv) MRF_MASKED(j * 64)
#pragma unroll 2
            for (int a = wv; a < NI2; a += 2) MRF_ITER2(JLO * 64 + a * 128)
            if constexpr (IBR)
                if ((NI2 & 1) == wv) MRF_ITER(JLO * 64 + NI2 * 128)
#pragma unroll
            for (int j = JT0; j < SEQ / 64; ++j)
                if (((j >> 1) & 1) == wv) MRF_MASKED(j * 64)
        } else {
            // valid region [P, SEQ-P): paired main + bridge + clamped partial
#pragma unroll 2
            for (int a = wv; a < MV2; a += 2) MRF_ITER2(P + a * 128)
            if constexpr (TV1)
                if ((MV2 & 1) == wv) MRF_ITER(P + MV2 * 128)
            if constexpr (REM != 0) {
                if (((MV2 + TV1) & 1) == wv) {
                    const int t = P + MV2 * 128 + TV1 * 64 + lane;
                    const int tr = (t < SEQ - P) ? t : (SEQ - P - 1);
                    const float* __restrict__ pb = y + tr - 4 * D;
                    float Cv = 0.0f;
#pragma unroll
                    for (int jj = 0; jj < 9; ++jj)
                        Cv = __builtin_fmaf(w[jj], pb[jj * D], Cv);
                    Cv = (t < SEQ - P) ? Cv : -3.402823466e38f;  // poison -> never > bias
#pragma unroll
                    for (int f = 0; f < NF; ++f)
                        cnt[f] += __popcll(__ballot(Cv > bs[f]));
                }
            }
        }

#undef MRF_ITER2
#undef MRF_ITER
#undef MRF_MASKED

        // ---- merge the unit's two waves' counts, wave0 writes out ----
        if (wv == 1 && lane == 0) {
#pragma unroll
            for (int f = 0; f < NF; ++f) cbuf[f] = cnt[f];
        }
        // barrier C: cbuf visible to wave0
        __syncthreads();
        if (wv == 0 && lane == 0) {
            const bool full = ((k & 1) == PAD1);
            const float invT = full ? (1.0f / (float)SEQ) : (1.0f / (float)RANGE);
            const int pos = full ? ((k - PAD1) >> 1) : (42 + ((k - (1 - PAD1)) >> 1));
            const int colb = CBASE + pos * NF;
#pragma unroll
            for (int f = 0; f < NF; ++f)
                out[(size_t)b * NFTOT + colb + f] = (float)(cnt[f] + cbuf[f]) * invT;
        }
    }
}

// Ledger (rounds 0-15):
//  - R9 (317us) is the per-wave frontier: WPB=2, 8KB shared ybuf, VGPR=64
//    EXACTLY (granule 16; 80-bucket costs 25% occ — R12). Structural variants
//    R10-R14 all regressed: WPB=4-shared (+36-54% VALU via 48-reg schedule),
//    dbuf pipeline (barriers weren't the cost), paired-k build (x/L2 traffic
//    wasn't the cost; FETCH even rose).
//  - Residency vs waves/block (VGPR<=64-bucket): 1w->7.2/CU, 2w->14.2,
//    4w-shared->18. Not LDS-capped (R13), not VGPR-capped, sublinear in
//    block fatness. R15 probes the one untried cell: 4-wave blocks whose
//    per-wave code is R9-VERBATIM (2 independent units) -> R10's residency
//    without R10's strangled allocation. Units pair slots s/s+14 (equal
//    parity) so shared barriers stay phase-aligned.
//  - Packed f32 FMA dead (R7/R12). Caps: generous (128) only (R1/R10).
extern "C" __global__ void __launch_bounds__(NUNIT * 2 * 64)
__attribute__((amdgpu_num_vgpr(128)))
mrf_kernel(const float* __restrict__ x, const float* __restrict__ kw,
           const float* __restrict__ cc, const float* __restrict__ bias,
           float* __restrict__ out) {
    __shared__ __align__(16) float ybuf[NUNIT][SEQ];   // 8KB private per unit
    __shared__ int cbuf[NUNIT][MAXNF];                 // per-unit count merge

    // XCD-chunked bijective swizzle (proven round 0): XCD x owns a contiguous
    // chunk of (b,i,sp) with b slowest -> concurrent blocks on an XCD share
    // ~1-2 b values -> x slices stay L2-resident. (R1 measured the
    // alternative: i slowest -> 1.75 GB of L2 misses, 1.7x slower.)
    constexpr int NGRID = NDIL * NBATCH * NSPAIR;      // 23296
    constexpr int CHUNK = NGRID / NXCD;                // 2912
    const int blk = (blockIdx.x % NXCD) * CHUNK + blockIdx.x / NXCD;

    const int sp = blk % NSPAIR;            // slot-pair index [0,14)
    const int rest = blk / NSPAIR;
    const int i = rest % NDIL;              // dilation index
    const int b = rest / NDIL;              // batch index (slowest)
    const int lane = threadIdx.x & 63;
    // wave id in block -> (unit, wave-within-unit), both SGPR-uniform
    const int wv4 = __builtin_amdgcn_readfirstlane((int)(threadIdx.x >> 6));
    const int unit = wv4 >> 1;
    const int uw = wv4 & 1;
    const int slot = sp + unit * NSPAIR;    // unit0: sp, unit1: sp+14 (same parity)

    const float* xb = x + (size_t)b * (NCH * SEQ);

    switch (i) {
#define MRF_CASE(I) case I: body<I>(kw, cc, bias, out, xb, ybuf[unit], cbuf[unit], b, slot, lane, uw); break;
        MRF_CASE(0)  MRF_CASE(1)  MRF_CASE(2)  MRF_CASE(3)  MRF_CASE(4)
        MRF_CASE(5)  MRF_CASE(6)  MRF_CASE(7)  MRF_CASE(8)  MRF_CASE(9)
        MRF_CASE(10) MRF_CASE(11) MRF_CASE(12) MRF_CASE(13) MRF_CASE(14)
        MRF_CASE(15) MRF_CASE(16) MRF_CASE(17) MRF_CASE(18) MRF_CASE(19)
        MRF_CASE(20) MRF_CASE(21) MRF_CASE(22) MRF_CASE(23) MRF_CASE(24)
        MRF_CASE(25)
#undef MRF_CASE
    }
}

extern "C" void kernel_launch(void* const* d_in, const int* in_sizes, int n_in,
                              void* d_out, int out_size, void* d_ws, size_t ws_size,
                              hipStream_t stream) {
    (void)in_sizes; (void)n_in; (void)d_ws; (void)ws_size; (void)out_size;
    const float* x    = (const float*)d_in[0];
    const float* kw   = (const float*)d_in[1];
    const float* cc   = (const float*)d_in[2];
    const float* bias = (const float*)d_in[3];
    float* out = (float*)d_out;

    mrf_kernel<<<dim3(NDIL * NBATCH * NSPAIR), dim3(NUNIT * 2 * 64), 0, stream>>>(x, kw, cc, bias, out);
}